// Round 10
// baseline (208.331 us; speedup 1.0000x reference)
//
#include <hip/hip_runtime.h>
#include <hip/hip_bf16.h>

#define N_ROWS 16384
#define D_COLS 2048
#define NUM_LABELS 1024
#define NUM_CAMS 8
#define NUM_SEG (NUM_LABELS * NUM_CAMS)   // 8192
#define MAXPER 64                          // list capacity per segment
#define GSEG 8                             // segments per block
#define NUM_BLOCKS (NUM_SEG / GSEG * 2)    // 2048 blocks: (group, half) -> 8/CU, ALL resident
#define FAST_R 4                           // register-cached rows/segment (P(cnt>4)~5%)
#define INFO_INTS 8                        // per-segment record: cnt, idx[0..3], pad -> 32 B
#define F4_PER_ROW (D_COLS / 4)            // 512 float4 per row

// ---------------- kernel 1: build per-segment row lists ----------------
__global__ void build_lists_kernel(const int* __restrict__ labels,
                                   const int* __restrict__ cams,
                                   int* __restrict__ counts,
                                   int* __restrict__ lists) {
    int i = blockIdx.x * blockDim.x + threadIdx.x;
    if (i < N_ROWS) {
        int seg = labels[i] * NUM_CAMS + cams[i];
        int pos = atomicAdd(&counts[seg], 1);
        if (pos < MAXPER) lists[seg * MAXPER + pos] = i;
    }
}

// ---------------- kernel 2: repack into 32B records, CLAMPED indices -------
// Invalid slots point at idx[0] (same row -> duplicate loads are L1 hits),
// so the consumer can issue ALL loads unconditionally with zero over-fetch.
__global__ __launch_bounds__(256) void repack_kernel(const int* __restrict__ counts,
                                                     const int* __restrict__ lists,
                                                     int* __restrict__ seginfo) {
    int seg = blockIdx.x * blockDim.x + threadIdx.x;
    if (seg < NUM_SEG) {
        int cnt = counts[seg];
        int c = cnt < FAST_R ? cnt : FAST_R;
        int first = (cnt > 0) ? lists[seg * MAXPER] : 0;
        int* o = seginfo + seg * INFO_INTS;
        o[0] = cnt;
#pragma unroll
        for (int r = 0; r < FAST_R; ++r)
            o[1 + r] = (r < c) ? lists[seg * MAXPER + r] : first;
        o[5] = 0; o[6] = 0; o[7] = 0;   // pad (keeps record deterministic)
    }
}

__device__ __forceinline__ float smooth_l1(float d) {
    float ad = fabsf(d);
    return ad < 1.0f ? 0.5f * d * d : ad - 0.5f;
}

// ---------------- kernel 3: one block per (8 segments, column-half) --------
// Metadata via block-uniform seginfo records -> scalar loads (cnt in SGPR).
// All FAST_R row loads UNCONDITIONAL (clamped indices) -> static vmcnt,
// ping-pong pipeline actually overlaps; masking via w in {0,1} in ALU.
__global__ __launch_bounds__(256, 8) void group_loss_kernel(const float* __restrict__ feats,
                                                            const int* __restrict__ seginfo,
                                                            const int* __restrict__ lists,
                                                            float* __restrict__ partials) {
    int bid  = blockIdx.x;
    int grp  = bid >> 1;
    int half = bid & 1;
    int tid  = threadIdx.x;
    int seg0 = grp * GSEG;

    const int* info = seginfo + (size_t)grp * GSEG * INFO_INTS;  // uniform -> s_load
    const float4* base = (const float4*)feats + (half * 256 + tid);
    float loss = 0.0f;

    // unconditional 4-row load for segment s; cnt returned via ref
    auto load4 = [&](float4* v, int s, int& cnt) {
        const int* rec = info + s * INFO_INTS;
        cnt = rec[0];
#pragma unroll
        for (int r = 0; r < FAST_R; ++r)
            v[r] = base[(size_t)rec[1 + r] * F4_PER_ROW];
    };

    // consume one segment: weighted sum, mean, SmoothL1 from registers
    auto consume = [&](const float4* v, int s, int cnt) {
        float mx = 0.f, my = 0.f, mz = 0.f, mw = 0.f;
#pragma unroll
        for (int r = 0; r < FAST_R; ++r) {
            float w = (r < cnt) ? 1.0f : 0.0f;
            mx = fmaf(w, v[r].x, mx);
            my = fmaf(w, v[r].y, my);
            mz = fmaf(w, v[r].z, mz);
            mw = fmaf(w, v[r].w, mw);
        }
        if (cnt > FAST_R) {                        // rare tail: stream-add
            for (int r = FAST_R; r < cnt && r < MAXPER; ++r) {
                float4 a = base[(size_t)lists[(seg0 + s) * MAXPER + r] * F4_PER_ROW];
                mx += a.x; my += a.y; mz += a.z; mw += a.w;
            }
        }
        float inv = 1.0f / (float)(cnt > 0 ? cnt : 1);
        mx *= inv; my *= inv; mz *= inv; mw *= inv;

#pragma unroll
        for (int r = 0; r < FAST_R; ++r) {
            float w = (r < cnt) ? 1.0f : 0.0f;
            loss += w * (smooth_l1(v[r].x - mx) + smooth_l1(v[r].y - my)
                       + smooth_l1(v[r].z - mz) + smooth_l1(v[r].w - mw));
        }
        if (cnt > FAST_R) {                        // rare tail: re-stream (L2-hot)
            for (int r = FAST_R; r < cnt && r < MAXPER; ++r) {
                float4 a = base[(size_t)lists[(seg0 + s) * MAXPER + r] * F4_PER_ROW];
                loss += smooth_l1(a.x - mx) + smooth_l1(a.y - my)
                      + smooth_l1(a.z - mz) + smooth_l1(a.w - mw);
            }
        }
    };

    // depth-2 pipeline: ping-pong register buffers, GSEG even
    float4 va[FAST_R], vb[FAST_R];
    int ca, cb;
    load4(va, 0, ca);
#pragma unroll 1
    for (int s = 0; s < GSEG; s += 2) {
        load4(vb, s + 1, cb);                 // in flight while consuming va
        consume(va, s, ca);
        if (s + 2 < GSEG)
            load4(va, s + 2, ca);             // in flight while consuming vb
        consume(vb, s + 1, cb);
    }

    // block reduction: wave64 shuffle then LDS across 4 waves
    for (int o = 32; o > 0; o >>= 1)
        loss += __shfl_down(loss, o, 64);

    __shared__ float wsum[4];
    int lane = tid & 63;
    int wid  = tid >> 6;
    if (lane == 0) wsum[wid] = loss;
    __syncthreads();
    if (tid == 0)
        partials[bid] = wsum[0] + wsum[1] + wsum[2] + wsum[3];
}

// ---------------- kernel 4: reduce partials -> scalar loss ----------------
__global__ __launch_bounds__(256) void reduce_kernel(const float* __restrict__ partials,
                                                     float* __restrict__ out) {
    int tid = threadIdx.x;
    float s = 0.0f;
    for (int i = tid; i < NUM_BLOCKS; i += 256)
        s += partials[i];

    for (int o = 32; o > 0; o >>= 1)
        s += __shfl_down(s, o, 64);

    __shared__ float wsum[4];
    int lane = tid & 63;
    int wid  = tid >> 6;
    if (lane == 0) wsum[wid] = s;
    __syncthreads();
    if (tid == 0)
        out[0] = (wsum[0] + wsum[1] + wsum[2] + wsum[3])
               * (1.0f / ((float)N_ROWS * (float)D_COLS));
}

extern "C" void kernel_launch(void* const* d_in, const int* in_sizes, int n_in,
                              void* d_out, int out_size, void* d_ws, size_t ws_size,
                              hipStream_t stream) {
    const float* feats = (const float*)d_in[0];
    const int* labels  = (const int*)d_in[1];
    const int* cams    = (const int*)d_in[2];
    float* out = (float*)d_out;

    // ws layout: counts[NUM_SEG] | lists[NUM_SEG*MAXPER] | seginfo[NUM_SEG*8] | partials[NUM_BLOCKS]
    int* counts     = (int*)d_ws;
    int* lists      = counts + NUM_SEG;
    int* seginfo    = lists + NUM_SEG * MAXPER;
    float* partials = (float*)(seginfo + NUM_SEG * INFO_INTS);

    hipMemsetAsync(counts, 0, NUM_SEG * sizeof(int), stream);   // only counts need zeroing

    build_lists_kernel<<<(N_ROWS + 255) / 256, 256, 0, stream>>>(labels, cams, counts, lists);
    repack_kernel<<<(NUM_SEG + 255) / 256, 256, 0, stream>>>(counts, lists, seginfo);
    group_loss_kernel<<<NUM_BLOCKS, 256, 0, stream>>>(feats, seginfo, lists, partials);
    reduce_kernel<<<1, 256, 0, stream>>>(partials, out);
}